// Round 2
// baseline (3222.258 us; speedup 1.0000x reference)
//
#include <hip/hip_runtime.h>
#include <math.h>

// Problem constants (from reference setup_inputs):
//   x,y: [8, 256, 64, 64] fp32; groups=4, eps=1e-6; 4 conv1x1 weights [256,256].
// Workspace usage: Qt,Kt,Vt,Ot each 8*4096*256*4 = 32MB -> 128MB, + stats 32KB.

namespace {
constexpr int kB   = 8;
constexpr int kC   = 256;
constexpr int kCPG = 64;     // channels per group (256/4)
constexpr int kHW  = 4096;   // 64*64
constexpr float kEps = 1e-6f;
}

// ---------------------------------------------------------------------------
// Kernel 1: GroupNorm statistics -> per-(tensor,b,c) affine scale/shift
// grid = 64 blocks (2 tensors * 8 batches * 4 groups), 256 threads
// ---------------------------------------------------------------------------
__global__ __launch_bounds__(256)
void gn_stats_kernel(const float* __restrict__ x, const float* __restrict__ y,
                     const float* __restrict__ gamma, const float* __restrict__ beta,
                     float* __restrict__ scaleX, float* __restrict__ shiftX,
                     float* __restrict__ scaleY, float* __restrict__ shiftY) {
  int blk = blockIdx.x;            // t*32 + b*4 + g
  int g = blk & 3;
  int b = (blk >> 2) & 7;
  int t = blk >> 5;
  const float* src = (t == 0 ? x : y) + ((size_t)b * kC + (size_t)g * kCPG) * kHW;
  const int N = kCPG * kHW;        // 262144
  float sum = 0.f, ssq = 0.f;
  for (int i = threadIdx.x * 4; i < N; i += 256 * 4) {
    float4 v = *(const float4*)(src + i);
    sum += v.x + v.y + v.z + v.w;
    ssq += v.x * v.x + v.y * v.y + v.z * v.z + v.w * v.w;
  }
  #pragma unroll
  for (int off = 32; off > 0; off >>= 1) {
    sum += __shfl_down(sum, off);
    ssq += __shfl_down(ssq, off);
  }
  __shared__ float rs[4], rq[4];
  __shared__ float sM, sR;
  int lane = threadIdx.x & 63, w = threadIdx.x >> 6;
  if (lane == 0) { rs[w] = sum; rq[w] = ssq; }
  __syncthreads();
  if (threadIdx.x == 0) {
    float s = rs[0] + rs[1] + rs[2] + rs[3];
    float q = rq[0] + rq[1] + rq[2] + rq[3];
    float mean = s / (float)N;
    float var  = q / (float)N - mean * mean;
    sM = mean;
    sR = rsqrtf(var + kEps);
  }
  __syncthreads();
  if (threadIdx.x < kCPG) {
    int c = g * kCPG + threadIdx.x;
    float sc = gamma[c] * sR;
    float sh = beta[c] - sM * sc;
    if (t == 0) { scaleX[b * kC + c] = sc; shiftX[b * kC + c] = sh; }
    else        { scaleY[b * kC + c] = sc; shiftY[b * kC + c] = sh; }
  }
}

// ---------------------------------------------------------------------------
// Kernel 2: QKV conv1x1 GEMM with fused normalization.
//   out[o,p] = sum_c W[o,c] * (X[c,p]*scale[c]+shift[c]) ; +bias; Q scaled 1/16.
// Written transposed: T[p][o]  (attention-friendly [position][channel]).
// grid.x = B * (HW/64) * (C/64) = 2048, grid.y = 3 (q,k,v); 256 threads.
// ---------------------------------------------------------------------------
__global__ __launch_bounds__(256)
void qkv_gemm_kernel(const float* __restrict__ x, const float* __restrict__ y,
                     const float* __restrict__ wq, const float* __restrict__ bq,
                     const float* __restrict__ wk, const float* __restrict__ bk,
                     const float* __restrict__ wv, const float* __restrict__ bv,
                     const float* __restrict__ scaleX, const float* __restrict__ shiftX,
                     const float* __restrict__ scaleY, const float* __restrict__ shiftY,
                     float* __restrict__ Qt, float* __restrict__ Kt, float* __restrict__ Vt) {
  int z  = blockIdx.y;                 // 0=q (from x), 1=k, 2=v (from y)
  int bi = blockIdx.x;
  int ot = bi & 3;                     // o-tile (4)
  int pt = (bi >> 2) & 63;             // p-tile (64)
  int b  = bi >> 8;
  const float* X    = (z == 0 ? x : y) + (size_t)b * kC * kHW;
  const float* W    = (z == 0 ? wq : (z == 1 ? wk : wv));
  const float* bias = (z == 0 ? bq : (z == 1 ? bk : bv));
  const float* SC   = (z == 0 ? scaleX : scaleY) + b * kC;
  const float* SH   = (z == 0 ? shiftX : shiftY) + b * kC;
  float* T = (z == 0 ? Qt : (z == 1 ? Kt : Vt)) + (size_t)b * kHW * kC;
  float osc = (z == 0) ? 0.0625f : 1.0f;   // fold score scale 1/sqrt(256) into Q

  __shared__ float Ws[32][68];   // [c][o] transposed
  __shared__ float Xs[32][68];   // [c][p] natural

  int tid = threadIdx.x;
  int ty = tid >> 4, tx = tid & 15;
  int obase = ot * 64, pbase = pt * 64;
  float acc[4][4] = {};

  for (int c0 = 0; c0 < kC; c0 += 32) {
    __syncthreads();
    {  // W tile [64o][32c] -> Ws[c][o]
      int o  = tid >> 2;
      int cb = (tid & 3) * 8;
      const float* s = W + (size_t)(obase + o) * kC + c0 + cb;
      float4 a0 = *(const float4*)(s);
      float4 a1 = *(const float4*)(s + 4);
      Ws[cb + 0][o] = a0.x; Ws[cb + 1][o] = a0.y; Ws[cb + 2][o] = a0.z; Ws[cb + 3][o] = a0.w;
      Ws[cb + 4][o] = a1.x; Ws[cb + 5][o] = a1.y; Ws[cb + 6][o] = a1.z; Ws[cb + 7][o] = a1.w;
    }
    {  // X tile [32c][64p] with fused affine -> Xs[c][p]
      int c  = tid >> 3;
      int pb = (tid & 7) * 8;
      const float* s = X + (size_t)(c0 + c) * kHW + pbase + pb;
      float sc = SC[c0 + c], sh = SH[c0 + c];
      float4 a0 = *(const float4*)(s);
      float4 a1 = *(const float4*)(s + 4);
      float4 r0 = make_float4(fmaf(a0.x, sc, sh), fmaf(a0.y, sc, sh), fmaf(a0.z, sc, sh), fmaf(a0.w, sc, sh));
      float4 r1 = make_float4(fmaf(a1.x, sc, sh), fmaf(a1.y, sc, sh), fmaf(a1.z, sc, sh), fmaf(a1.w, sc, sh));
      *(float4*)&Xs[c][pb]     = r0;
      *(float4*)&Xs[c][pb + 4] = r1;
    }
    __syncthreads();
    #pragma unroll
    for (int kk = 0; kk < 32; ++kk) {
      float4 av = *(const float4*)&Ws[kk][ty * 4];
      float4 bv4 = *(const float4*)&Xs[kk][tx * 4];
      float a[4] = {av.x, av.y, av.z, av.w};
      float bb[4] = {bv4.x, bv4.y, bv4.z, bv4.w};
      #pragma unroll
      for (int i = 0; i < 4; ++i)
        #pragma unroll
        for (int j = 0; j < 4; ++j) acc[i][j] = fmaf(a[i], bb[j], acc[i][j]);
    }
  }
  float bz[4];
  #pragma unroll
  for (int i = 0; i < 4; ++i) bz[i] = bias[obase + ty * 4 + i];
  #pragma unroll
  for (int j = 0; j < 4; ++j) {
    int p = pbase + tx * 4 + j;
    float4 v = make_float4((acc[0][j] + bz[0]) * osc, (acc[1][j] + bz[1]) * osc,
                           (acc[2][j] + bz[2]) * osc, (acc[3][j] + bz[3]) * osc);
    *(float4*)&T[(size_t)p * kC + obase + ty * 4] = v;
  }
}

// ---------------------------------------------------------------------------
// Kernel 3: fp32 flash attention.  Q,K,V as [b][p][c] (Q pre-scaled by 1/16).
// One block per (b, 64-query tile); online softmax over 64 key tiles.
// Thread (ty,tx): scores 4q x 4k; output 4q x 16c; 256 threads.
// ---------------------------------------------------------------------------
__global__ __launch_bounds__(256)
void flash_kernel(const float* __restrict__ Qt, const float* __restrict__ Kt,
                  const float* __restrict__ Vt, float* __restrict__ Ot) {
  int b  = blockIdx.x >> 6;
  int qt = blockIdx.x & 63;
  int qbase = qt * 64;
  const float* Q = Qt + (size_t)b * kHW * kC;
  const float* K = Kt + (size_t)b * kHW * kC;
  const float* V = Vt + (size_t)b * kHW * kC;

  __shared__ float lds0[64][68];   // Q chunk [c][q]  /  P [k][q]
  __shared__ float lds1[64][68];   // K chunk [c][k]  /  V chunk [k][c]

  int tid = threadIdx.x;
  int ty = tid >> 4, tx = tid & 15;
  int lr  = tid >> 2;           // staging row 0..63
  int lcb = (tid & 3) * 16;     // staging col base

  float accO[4][16] = {};
  float m[4], l[4];
  #pragma unroll
  for (int i = 0; i < 4; ++i) { m[i] = -1e30f; l[i] = 0.f; }

  for (int kt = 0; kt < 64; ++kt) {
    int kbase = kt * 64;
    float accS[4][4] = {};
    // ---- Phase A: S = Q^T K over 4 chunks of 64 channels ----
    for (int cc = 0; cc < 4; ++cc) {
      __syncthreads();
      {
        const float* s = Q + (size_t)(qbase + lr) * kC + cc * 64 + lcb;
        float4 v0 = *(const float4*)(s);
        float4 v1 = *(const float4*)(s + 4);
        float4 v2 = *(const float4*)(s + 8);
        float4 v3 = *(const float4*)(s + 12);
        lds0[lcb + 0][lr] = v0.x;  lds0[lcb + 1][lr] = v0.y;  lds0[lcb + 2][lr] = v0.z;  lds0[lcb + 3][lr] = v0.w;
        lds0[lcb + 4][lr] = v1.x;  lds0[lcb + 5][lr] = v1.y;  lds0[lcb + 6][lr] = v1.z;  lds0[lcb + 7][lr] = v1.w;
        lds0[lcb + 8][lr] = v2.x;  lds0[lcb + 9][lr] = v2.y;  lds0[lcb +10][lr] = v2.z;  lds0[lcb +11][lr] = v2.w;
        lds0[lcb +12][lr] = v3.x;  lds0[lcb +13][lr] = v3.y;  lds0[lcb +14][lr] = v3.z;  lds0[lcb +15][lr] = v3.w;
      }
      {
        const float* s = K + (size_t)(kbase + lr) * kC + cc * 64 + lcb;
        float4 v0 = *(const float4*)(s);
        float4 v1 = *(const float4*)(s + 4);
        float4 v2 = *(const float4*)(s + 8);
        float4 v3 = *(const float4*)(s + 12);
        lds1[lcb + 0][lr] = v0.x;  lds1[lcb + 1][lr] = v0.y;  lds1[lcb + 2][lr] = v0.z;  lds1[lcb + 3][lr] = v0.w;
        lds1[lcb + 4][lr] = v1.x;  lds1[lcb + 5][lr] = v1.y;  lds1[lcb + 6][lr] = v1.z;  lds1[lcb + 7][lr] = v1.w;
        lds1[lcb + 8][lr] = v2.x;  lds1[lcb + 9][lr] = v2.y;  lds1[lcb +10][lr] = v2.z;  lds1[lcb +11][lr] = v2.w;
        lds1[lcb +12][lr] = v3.x;  lds1[lcb +13][lr] = v3.y;  lds1[lcb +14][lr] = v3.z;  lds1[lcb +15][lr] = v3.w;
      }
      __syncthreads();
      #pragma unroll
      for (int kk = 0; kk < 64; ++kk) {
        float4 qv = *(const float4*)&lds0[kk][ty * 4];
        float4 kv = *(const float4*)&lds1[kk][tx * 4];
        float qa[4] = {qv.x, qv.y, qv.z, qv.w};
        float ka[4] = {kv.x, kv.y, kv.z, kv.w};
        #pragma unroll
        for (int i = 0; i < 4; ++i)
          #pragma unroll
          for (int j = 0; j < 4; ++j) accS[i][j] = fmaf(qa[i], ka[j], accS[i][j]);
      }
    }
    // ---- Phase B: online softmax (registers + 16-lane shuffles) ----
    float p[4][4];
    #pragma unroll
    for (int i = 0; i < 4; ++i) {
      float tm = fmaxf(fmaxf(accS[i][0], accS[i][1]), fmaxf(accS[i][2], accS[i][3]));
      #pragma unroll
      for (int off = 1; off < 16; off <<= 1) tm = fmaxf(tm, __shfl_xor(tm, off));
      float mn = fmaxf(m[i], tm);
      float f  = __expf(m[i] - mn);
      float rsum = 0.f;
      #pragma unroll
      for (int j = 0; j < 4; ++j) { p[i][j] = __expf(accS[i][j] - mn); rsum += p[i][j]; }
      #pragma unroll
      for (int off = 1; off < 16; off <<= 1) rsum += __shfl_xor(rsum, off);
      l[i] = l[i] * f + rsum;
      m[i] = mn;
      #pragma unroll
      for (int j2 = 0; j2 < 16; ++j2) accO[i][j2] *= f;
    }
    __syncthreads();                    // phase-A LDS reads complete
    #pragma unroll
    for (int i = 0; i < 4; ++i)
      #pragma unroll
      for (int j = 0; j < 4; ++j) lds0[tx * 4 + j][ty * 4 + i] = p[i][j];   // P [k][q]
    // ---- Phase C: O += P * V over 4 chunks of 64 channels ----
    for (int cc = 0; cc < 4; ++cc) {
      __syncthreads();
      {
        const float* s = V + (size_t)(kbase + lr) * kC + cc * 64 + lcb;
        float4 v0 = *(const float4*)(s);
        float4 v1 = *(const float4*)(s + 4);
        float4 v2 = *(const float4*)(s + 8);
        float4 v3 = *(const float4*)(s + 12);
        *(float4*)&lds1[lr][lcb]      = v0;
        *(float4*)&lds1[lr][lcb + 4]  = v1;
        *(float4*)&lds1[lr][lcb + 8]  = v2;
        *(float4*)&lds1[lr][lcb + 12] = v3;
      }
      __syncthreads();
      #pragma unroll
      for (int kk = 0; kk < 64; ++kk) {
        float4 pv = *(const float4*)&lds0[kk][ty * 4];
        float4 vv = *(const float4*)&lds1[kk][tx * 4];
        float pa[4] = {pv.x, pv.y, pv.z, pv.w};
        float va[4] = {vv.x, vv.y, vv.z, vv.w};
        #pragma unroll
        for (int i = 0; i < 4; ++i)
          #pragma unroll
          for (int j = 0; j < 4; ++j) accO[i][cc * 4 + j] = fmaf(pa[i], va[j], accO[i][cc * 4 + j]);
      }
    }
  }
  // ---- epilogue: normalize by l, write Ot[p][c] ----
  float* O = Ot + (size_t)b * kHW * kC;
  #pragma unroll
  for (int i = 0; i < 4; ++i) {
    float inv = 1.0f / l[i];
    int pp = qbase + ty * 4 + i;
    #pragma unroll
    for (int cc = 0; cc < 4; ++cc) {
      float4 v = make_float4(accO[i][cc * 4 + 0] * inv, accO[i][cc * 4 + 1] * inv,
                             accO[i][cc * 4 + 2] * inv, accO[i][cc * 4 + 3] * inv);
      *(float4*)&O[(size_t)pp * kC + cc * 64 + tx * 4] = v;
    }
  }
}

// ---------------------------------------------------------------------------
// Kernel 4: proj conv1x1 + residual.  out[b][o][p] = wp . Ot[b][p][:] + bp + x
// grid = B * (HW/64) * (C/64) = 2048 blocks, 256 threads.
// ---------------------------------------------------------------------------
__global__ __launch_bounds__(256)
void proj_kernel(const float* __restrict__ Ot, const float* __restrict__ wp,
                 const float* __restrict__ bp, const float* __restrict__ x,
                 float* __restrict__ out) {
  int bi = blockIdx.x;
  int ot = bi & 3;
  int pt = (bi >> 2) & 63;
  int b  = bi >> 8;
  const float* Ob = Ot + (size_t)b * kHW * kC;
  int obase = ot * 64, pbase = pt * 64;

  __shared__ float Ws[32][68];   // [c][o]
  __shared__ float Os[32][68];   // [c][p]
  int tid = threadIdx.x;
  int ty = tid >> 4, tx = tid & 15;
  float acc[4][4] = {};

  for (int c0 = 0; c0 < kC; c0 += 32) {
    __syncthreads();
    {
      int o  = tid >> 2;
      int cb = (tid & 3) * 8;
      const float* s = wp + (size_t)(obase + o) * kC + c0 + cb;
      float4 a0 = *(const float4*)(s);
      float4 a1 = *(const float4*)(s + 4);
      Ws[cb + 0][o] = a0.x; Ws[cb + 1][o] = a0.y; Ws[cb + 2][o] = a0.z; Ws[cb + 3][o] = a0.w;
      Ws[cb + 4][o] = a1.x; Ws[cb + 5][o] = a1.y; Ws[cb + 6][o] = a1.z; Ws[cb + 7][o] = a1.w;
    }
    {
      int pr = tid >> 2;
      int cb = (tid & 3) * 8;
      const float* s = Ob + (size_t)(pbase + pr) * kC + c0 + cb;
      float4 a0 = *(const float4*)(s);
      float4 a1 = *(const float4*)(s + 4);
      Os[cb + 0][pr] = a0.x; Os[cb + 1][pr] = a0.y; Os[cb + 2][pr] = a0.z; Os[cb + 3][pr] = a0.w;
      Os[cb + 4][pr] = a1.x; Os[cb + 5][pr] = a1.y; Os[cb + 6][pr] = a1.z; Os[cb + 7][pr] = a1.w;
    }
    __syncthreads();
    #pragma unroll
    for (int kk = 0; kk < 32; ++kk) {
      float4 av = *(const float4*)&Ws[kk][ty * 4];
      float4 bv4 = *(const float4*)&Os[kk][tx * 4];
      float a[4] = {av.x, av.y, av.z, av.w};
      float bb[4] = {bv4.x, bv4.y, bv4.z, bv4.w};
      #pragma unroll
      for (int i = 0; i < 4; ++i)
        #pragma unroll
        for (int j = 0; j < 4; ++j) acc[i][j] = fmaf(a[i], bb[j], acc[i][j]);
    }
  }
  #pragma unroll
  for (int i = 0; i < 4; ++i) {
    int o = obase + ty * 4 + i;
    float bias = bp[o];
    const float* xr = x   + ((size_t)b * kC + o) * kHW + pbase + tx * 4;
    float*       orow = out + ((size_t)b * kC + o) * kHW + pbase + tx * 4;
    float4 xv = *(const float4*)xr;
    float4 v = make_float4(acc[i][0] + bias + xv.x, acc[i][1] + bias + xv.y,
                           acc[i][2] + bias + xv.z, acc[i][3] + bias + xv.w);
    *(float4*)orow = v;
  }
}

// ---------------------------------------------------------------------------
extern "C" void kernel_launch(void* const* d_in, const int* in_sizes, int n_in,
                              void* d_out, int out_size, void* d_ws, size_t ws_size,
                              hipStream_t stream) {
  (void)in_sizes; (void)n_in; (void)out_size;
  const float* x     = (const float*)d_in[0];
  const float* y     = (const float*)d_in[1];
  const float* gamma = (const float*)d_in[2];
  const float* beta  = (const float*)d_in[3];
  const float* wq    = (const float*)d_in[4];
  const float* bq    = (const float*)d_in[5];
  const float* wk    = (const float*)d_in[6];
  const float* bk    = (const float*)d_in[7];
  const float* wv    = (const float*)d_in[8];
  const float* bv    = (const float*)d_in[9];
  const float* wp    = (const float*)d_in[10];
  const float* bp    = (const float*)d_in[11];
  float* out = (float*)d_out;

  char* ws = (char*)d_ws;
  size_t tsz = (size_t)kB * kHW * kC * sizeof(float);   // 32 MB
  size_t need = 4 * tsz + 4 * (size_t)kB * kC * sizeof(float);
  if (ws_size < need) return;   // refuse to scribble OOB (would fault the container)

  float* Qt = (float*)(ws);
  float* Kt = (float*)(ws + tsz);
  float* Vt = (float*)(ws + 2 * tsz);
  float* Ot = (float*)(ws + 3 * tsz);
  float* scaleX = (float*)(ws + 4 * tsz);
  float* shiftX = scaleX + kB * kC;
  float* scaleY = shiftX + kB * kC;
  float* shiftY = scaleY + kB * kC;

  gn_stats_kernel<<<dim3(64), dim3(256), 0, stream>>>(
      x, y, gamma, beta, scaleX, shiftX, scaleY, shiftY);
  qkv_gemm_kernel<<<dim3(kB * 64 * 4, 3), dim3(256), 0, stream>>>(
      x, y, wq, bq, wk, bk, wv, bv, scaleX, shiftX, scaleY, shiftY, Qt, Kt, Vt);
  flash_kernel<<<dim3(kB * 64), dim3(256), 0, stream>>>(Qt, Kt, Vt, Ot);
  proj_kernel<<<dim3(kB * 64 * 4), dim3(256), 0, stream>>>(Ot, wp, bp, x, out);
}

// Round 3
// 991.618 us; speedup vs baseline: 3.2495x; 3.2495x over previous
//
#include <hip/hip_runtime.h>
#include <math.h>

// AttnBlock fused pipeline, MFMA edition.
//   x,y: [8, 256, 64, 64] fp32; GN groups=4 eps=1e-6; 4 conv1x1 weights [256,256].
// Attention runs on bf16 MFMA: Q,K as hi+lo bf16 pairs (3-MFMA fp32-class scores),
// P,V plain bf16. Workspace: Qh,Ql,Kh,Kl,Vh (bf16, 16MB each) + Ot (fp32, 32MB) + stats.

namespace {
constexpr int kB   = 8;
constexpr int kC   = 256;
constexpr int kCPG = 64;
constexpr int kHW  = 4096;
constexpr float kEps = 1e-6f;
}

typedef short bf16x8 __attribute__((ext_vector_type(8)));   // 8 bf16 in 4 VGPRs
typedef float f32x4  __attribute__((ext_vector_type(4)));

#define MFMA16(a, b, c) __builtin_amdgcn_mfma_f32_16x16x32_bf16((a), (b), (c), 0, 0, 0)

__device__ __forceinline__ unsigned short f2bf(float v) {   // RNE fp32 -> bf16 bits
  unsigned u = __float_as_uint(v);
  u += 0x7FFFu + ((u >> 16) & 1u);
  return (unsigned short)(u >> 16);
}
__device__ __forceinline__ float bf2f(unsigned short h) {
  return __uint_as_float(((unsigned)h) << 16);
}

// ---------------------------------------------------------------------------
// Kernel 1: GroupNorm statistics -> per-(tensor,b,c) scale/shift  (unchanged)
// ---------------------------------------------------------------------------
__global__ __launch_bounds__(256)
void gn_stats_kernel(const float* __restrict__ x, const float* __restrict__ y,
                     const float* __restrict__ gamma, const float* __restrict__ beta,
                     float* __restrict__ scaleX, float* __restrict__ shiftX,
                     float* __restrict__ scaleY, float* __restrict__ shiftY) {
  int blk = blockIdx.x;            // t*32 + b*4 + g
  int g = blk & 3;
  int b = (blk >> 2) & 7;
  int t = blk >> 5;
  const float* src = (t == 0 ? x : y) + ((size_t)b * kC + (size_t)g * kCPG) * kHW;
  const int N = kCPG * kHW;
  float sum = 0.f, ssq = 0.f;
  for (int i = threadIdx.x * 4; i < N; i += 256 * 4) {
    float4 v = *(const float4*)(src + i);
    sum += v.x + v.y + v.z + v.w;
    ssq += v.x * v.x + v.y * v.y + v.z * v.z + v.w * v.w;
  }
  #pragma unroll
  for (int off = 32; off > 0; off >>= 1) {
    sum += __shfl_down(sum, off);
    ssq += __shfl_down(ssq, off);
  }
  __shared__ float rs[4], rq[4];
  __shared__ float sM, sR;
  int lane = threadIdx.x & 63, w = threadIdx.x >> 6;
  if (lane == 0) { rs[w] = sum; rq[w] = ssq; }
  __syncthreads();
  if (threadIdx.x == 0) {
    float s = rs[0] + rs[1] + rs[2] + rs[3];
    float q = rq[0] + rq[1] + rq[2] + rq[3];
    float mean = s / (float)N;
    float var  = q / (float)N - mean * mean;
    sM = mean;
    sR = rsqrtf(var + kEps);
  }
  __syncthreads();
  if (threadIdx.x < kCPG) {
    int c = g * kCPG + threadIdx.x;
    float sc = gamma[c] * sR;
    float sh = beta[c] - sM * sc;
    if (t == 0) { scaleX[b * kC + c] = sc; shiftX[b * kC + c] = sh; }
    else        { scaleY[b * kC + c] = sc; shiftY[b * kC + c] = sh; }
  }
}

// ---------------------------------------------------------------------------
// Kernel 2: QKV conv1x1 GEMM, fused GN affine; emits bf16 forms for MFMA flash.
//   Q (z=0): Qh/Ql [p][c]  (1/16 score scale folded in — exact pow2)
//   K (z=1): Kh/Kl [p][c]
//   V (z=2): Vh    [c][p]
// ---------------------------------------------------------------------------
__global__ __launch_bounds__(256)
void qkv_gemm_kernel(const float* __restrict__ x, const float* __restrict__ y,
                     const float* __restrict__ wq, const float* __restrict__ bq,
                     const float* __restrict__ wk, const float* __restrict__ bk,
                     const float* __restrict__ wv, const float* __restrict__ bv,
                     const float* __restrict__ scaleX, const float* __restrict__ shiftX,
                     const float* __restrict__ scaleY, const float* __restrict__ shiftY,
                     unsigned short* __restrict__ Qh, unsigned short* __restrict__ Ql,
                     unsigned short* __restrict__ Kh, unsigned short* __restrict__ Kl,
                     unsigned short* __restrict__ Vh) {
  int z  = blockIdx.y;                 // 0=q (from x), 1=k, 2=v (from y)
  int bi = blockIdx.x;
  int ot = bi & 3;
  int pt = (bi >> 2) & 63;
  int b  = bi >> 8;
  const float* X    = (z == 0 ? x : y) + (size_t)b * kC * kHW;
  const float* W    = (z == 0 ? wq : (z == 1 ? wk : wv));
  const float* bias = (z == 0 ? bq : (z == 1 ? bk : bv));
  const float* SC   = (z == 0 ? scaleX : scaleY) + b * kC;
  const float* SH   = (z == 0 ? shiftX : shiftY) + b * kC;
  float osc = (z == 0) ? 0.0625f : 1.0f;

  __shared__ float Ws[32][68];   // [c][o]
  __shared__ float Xs[32][68];   // [c][p]

  int tid = threadIdx.x;
  int ty = tid >> 4, tx = tid & 15;
  int obase = ot * 64, pbase = pt * 64;
  float acc[4][4] = {};

  for (int c0 = 0; c0 < kC; c0 += 32) {
    __syncthreads();
    {  // W tile [64o][32c] -> Ws[c][o]
      int o  = tid >> 2;
      int cb = (tid & 3) * 8;
      const float* s = W + (size_t)(obase + o) * kC + c0 + cb;
      float4 a0 = *(const float4*)(s);
      float4 a1 = *(const float4*)(s + 4);
      Ws[cb + 0][o] = a0.x; Ws[cb + 1][o] = a0.y; Ws[cb + 2][o] = a0.z; Ws[cb + 3][o] = a0.w;
      Ws[cb + 4][o] = a1.x; Ws[cb + 5][o] = a1.y; Ws[cb + 6][o] = a1.z; Ws[cb + 7][o] = a1.w;
    }
    {  // X tile [32c][64p] fused affine -> Xs[c][p]
      int c  = tid >> 3;
      int pb = (tid & 7) * 8;
      const float* s = X + (size_t)(c0 + c) * kHW + pbase + pb;
      float sc = SC[c0 + c], sh = SH[c0 + c];
      float4 a0 = *(const float4*)(s);
      float4 a1 = *(const float4*)(s + 4);
      float4 r0 = make_float4(fmaf(a0.x, sc, sh), fmaf(a0.y, sc, sh), fmaf(a0.z, sc, sh), fmaf(a0.w, sc, sh));
      float4 r1 = make_float4(fmaf(a1.x, sc, sh), fmaf(a1.y, sc, sh), fmaf(a1.z, sc, sh), fmaf(a1.w, sc, sh));
      *(float4*)&Xs[c][pb]     = r0;
      *(float4*)&Xs[c][pb + 4] = r1;
    }
    __syncthreads();
    #pragma unroll
    for (int kk = 0; kk < 32; ++kk) {
      float4 av  = *(const float4*)&Ws[kk][ty * 4];
      float4 bv4 = *(const float4*)&Xs[kk][tx * 4];
      float a[4]  = {av.x, av.y, av.z, av.w};
      float bb[4] = {bv4.x, bv4.y, bv4.z, bv4.w};
      #pragma unroll
      for (int i = 0; i < 4; ++i)
        #pragma unroll
        for (int j = 0; j < 4; ++j) acc[i][j] = fmaf(a[i], bb[j], acc[i][j]);
    }
  }
  float bz[4];
  #pragma unroll
  for (int i = 0; i < 4; ++i) bz[i] = bias[obase + ty * 4 + i];

  if (z < 2) {
    unsigned short* Th = (z == 0) ? Qh : Kh;
    unsigned short* Tl = (z == 0) ? Ql : Kl;
    Th += (size_t)b * kHW * kC;
    Tl += (size_t)b * kHW * kC;
    #pragma unroll
    for (int j = 0; j < 4; ++j) {
      int p = pbase + tx * 4 + j;
      ushort4 hh, ll;
      float v0 = (acc[0][j] + bz[0]) * osc;
      float v1 = (acc[1][j] + bz[1]) * osc;
      float v2 = (acc[2][j] + bz[2]) * osc;
      float v3 = (acc[3][j] + bz[3]) * osc;
      hh.x = f2bf(v0); ll.x = f2bf(v0 - bf2f(hh.x));
      hh.y = f2bf(v1); ll.y = f2bf(v1 - bf2f(hh.y));
      hh.z = f2bf(v2); ll.z = f2bf(v2 - bf2f(hh.z));
      hh.w = f2bf(v3); ll.w = f2bf(v3 - bf2f(hh.w));
      *(ushort4*)&Th[(size_t)p * kC + obase + ty * 4] = hh;
      *(ushort4*)&Tl[(size_t)p * kC + obase + ty * 4] = ll;
    }
  } else {
    unsigned short* Vb = Vh + (size_t)b * kHW * kC;   // [c][p]
    #pragma unroll
    for (int i = 0; i < 4; ++i) {
      int o = obase + ty * 4 + i;
      ushort4 vv;
      vv.x = f2bf(acc[i][0] + bz[i]);
      vv.y = f2bf(acc[i][1] + bz[i]);
      vv.z = f2bf(acc[i][2] + bz[i]);
      vv.w = f2bf(acc[i][3] + bz[i]);
      *(ushort4*)&Vb[(size_t)o * kHW + pbase + tx * 4] = vv;
    }
  }
}

// ---------------------------------------------------------------------------
// Kernel 3: MFMA flash attention.
//   Block: 64 queries, 256 threads = 4 waves, each wave owns a 16-q strip.
//   kt loop: 128 tiles of 32 keys. S via 3-MFMA hi/lo bf16 (fp32-class),
//   softmax wave-local (16-lane shfl groups), PV plain bf16 MFMA.
//   grid 512; bid -> b = bid&7 (XCD locality: one batch per XCD), qt = bid>>3.
// ---------------------------------------------------------------------------
__global__ __launch_bounds__(256, 2)
void flash_mfma_kernel(const unsigned short* __restrict__ Qh, const unsigned short* __restrict__ Ql,
                       const unsigned short* __restrict__ Kh, const unsigned short* __restrict__ Kl,
                       const unsigned short* __restrict__ Vh, float* __restrict__ Ot) {
  int bid = blockIdx.x;
  int b  = bid & 7;
  int qt = bid >> 3;
  const size_t toff = (size_t)b * kHW * kC;
  const unsigned short* Qhb = Qh + toff;
  const unsigned short* Qlb = Ql + toff;
  const unsigned short* Khb = Kh + toff;
  const unsigned short* Klb = Kl + toff;
  const unsigned short* Vhb = Vh + toff;   // [c][k]
  float* O = Ot + toff;                    // [q][c]

  __shared__ short Kh_s[32][264];   // [key][c] +8 pad
  __shared__ short Kl_s[32][264];
  __shared__ short V_s[256][40];    // [c][key] +8 pad
  __shared__ short P_s[64][40];     // [q][key] +8 pad (wave-private rows)

  int tid  = threadIdx.x;
  int lane = tid & 63;
  int w    = tid >> 6;
  int lrow = lane & 15;      // m/n fragment index
  int lgrp = lane >> 4;      // k-group

  // ---- Q fragments in registers (A-frags, hi+lo), loaded once ----
  bf16x8 qfh[8], qfl[8];
  {
    int qrow = qt * 64 + w * 16 + lrow;
    const unsigned short* qb = Qhb + (size_t)qrow * kC + lgrp * 8;
    const unsigned short* ql_ = Qlb + (size_t)qrow * kC + lgrp * 8;
    #pragma unroll
    for (int cc = 0; cc < 8; ++cc) {
      qfh[cc] = *(const bf16x8*)(qb  + cc * 32);
      qfl[cc] = *(const bf16x8*)(ql_ + cc * 32);
    }
  }

  f32x4 accO[16];
  #pragma unroll
  for (int nt = 0; nt < 16; ++nt) accO[nt] = (f32x4){0.f, 0.f, 0.f, 0.f};
  float m_[4], l_[4];
  #pragma unroll
  for (int r = 0; r < 4; ++r) { m_[r] = -1e30f; l_[r] = 0.f; }

  for (int kt = 0; kt < 128; ++kt) {
    int kbase = kt * 32;
    __syncthreads();   // previous PV reads of V_s done
    // ---- stage K (hi+lo) [32][256] and V^T [256][32] ----
    {
      int colg = tid & 31;        // 8-bf16 group within a K row
      int r0   = tid >> 5;        // 0..7
      #pragma unroll
      for (int rep = 0; rep < 4; ++rep) {
        int row = r0 + rep * 8;
        *(int4*)&Kh_s[row][colg * 8] =
            *(const int4*)(Khb + (size_t)(kbase + row) * kC + colg * 8);
        *(int4*)&Kl_s[row][colg * 8] =
            *(const int4*)(Klb + (size_t)(kbase + row) * kC + colg * 8);
      }
      int part = tid & 3;         // 8-key group within a V row
      int c0   = tid >> 2;        // 0..63
      #pragma unroll
      for (int rep = 0; rep < 4; ++rep) {
        int c = c0 + rep * 64;
        *(int4*)&V_s[c][part * 8] =
            *(const int4*)(Vhb + (size_t)c * kHW + kbase + part * 8);
      }
    }
    __syncthreads();

    // ---- QK^T: S[16q x 32k] per wave, two 16-key n-tiles, hi/lo 3-MFMA ----
    f32x4 s0 = (f32x4){0.f, 0.f, 0.f, 0.f};
    f32x4 s1 = (f32x4){0.f, 0.f, 0.f, 0.f};
    #pragma unroll
    for (int cc = 0; cc < 8; ++cc) {
      int coff = cc * 32 + lgrp * 8;
      bf16x8 k0h = *(const bf16x8*)&Kh_s[lrow][coff];
      bf16x8 k0l = *(const bf16x8*)&Kl_s[lrow][coff];
      bf16x8 k1h = *(const bf16x8*)&Kh_s[16 + lrow][coff];
      bf16x8 k1l = *(const bf16x8*)&Kl_s[16 + lrow][coff];
      s0 = MFMA16(qfh[cc], k0h, s0);
      s0 = MFMA16(qfh[cc], k0l, s0);
      s0 = MFMA16(qfl[cc], k0h, s0);
      s1 = MFMA16(qfh[cc], k1h, s1);
      s1 = MFMA16(qfh[cc], k1l, s1);
      s1 = MFMA16(qfl[cc], k1h, s1);
    }

    // ---- online softmax (wave-local; rows owned by 16-lane groups) ----
    int prow = w * 16 + lgrp * 4;
    #pragma unroll
    for (int r = 0; r < 4; ++r) {
      float mx = fmaxf(s0[r], s1[r]);
      mx = fmaxf(mx, __shfl_xor(mx, 1));
      mx = fmaxf(mx, __shfl_xor(mx, 2));
      mx = fmaxf(mx, __shfl_xor(mx, 4));
      mx = fmaxf(mx, __shfl_xor(mx, 8));
      float mn = fmaxf(m_[r], mx);
      float f  = __expf(m_[r] - mn);
      unsigned short u0 = f2bf(__expf(s0[r] - mn));
      unsigned short u1 = f2bf(__expf(s1[r] - mn));
      float sum = bf2f(u0) + bf2f(u1);     // sum what PV actually uses
      sum += __shfl_xor(sum, 1);
      sum += __shfl_xor(sum, 2);
      sum += __shfl_xor(sum, 4);
      sum += __shfl_xor(sum, 8);
      l_[r] = l_[r] * f + sum;
      m_[r] = mn;
      P_s[prow + r][lrow]      = (short)u0;
      P_s[prow + r][16 + lrow] = (short)u1;
      #pragma unroll
      for (int nt = 0; nt < 16; ++nt) accO[nt][r] *= f;
    }
    __syncthreads();   // P_s visible (conservative; rows are wave-private)

    // ---- PV: O[16q x 256c] += P[16q x 32k] * V[32k x 256c] ----
    bf16x8 pa = *(const bf16x8*)&P_s[w * 16 + lrow][lgrp * 8];
    #pragma unroll
    for (int nt = 0; nt < 16; ++nt) {
      bf16x8 vb = *(const bf16x8*)&V_s[nt * 16 + lrow][lgrp * 8];
      accO[nt] = MFMA16(pa, vb, accO[nt]);
    }
  }

  // ---- epilogue: normalize, write O [q][c] fp32 ----
  float inv[4];
  #pragma unroll
  for (int r = 0; r < 4; ++r) inv[r] = 1.0f / l_[r];
  int qbase = qt * 64 + w * 16 + lgrp * 4;
  #pragma unroll
  for (int nt = 0; nt < 16; ++nt) {
    #pragma unroll
    for (int r = 0; r < 4; ++r) {
      O[(size_t)(qbase + r) * kC + nt * 16 + lrow] = accO[nt][r] * inv[r];
    }
  }
}

// ---------------------------------------------------------------------------
// Kernel 4: proj conv1x1 + residual (unchanged; Ot is [p][c] fp32)
// ---------------------------------------------------------------------------
__global__ __launch_bounds__(256)
void proj_kernel(const float* __restrict__ Ot, const float* __restrict__ wp,
                 const float* __restrict__ bp, const float* __restrict__ x,
                 float* __restrict__ out) {
  int bi = blockIdx.x;
  int ot = bi & 3;
  int pt = (bi >> 2) & 63;
  int b  = bi >> 8;
  const float* Ob = Ot + (size_t)b * kHW * kC;
  int obase = ot * 64, pbase = pt * 64;

  __shared__ float Ws[32][68];
  __shared__ float Os[32][68];
  int tid = threadIdx.x;
  int ty = tid >> 4, tx = tid & 15;
  float acc[4][4] = {};

  for (int c0 = 0; c0 < kC; c0 += 32) {
    __syncthreads();
    {
      int o  = tid >> 2;
      int cb = (tid & 3) * 8;
      const float* s = wp + (size_t)(obase + o) * kC + c0 + cb;
      float4 a0 = *(const float4*)(s);
      float4 a1 = *(const float4*)(s + 4);
      Ws[cb + 0][o] = a0.x; Ws[cb + 1][o] = a0.y; Ws[cb + 2][o] = a0.z; Ws[cb + 3][o] = a0.w;
      Ws[cb + 4][o] = a1.x; Ws[cb + 5][o] = a1.y; Ws[cb + 6][o] = a1.z; Ws[cb + 7][o] = a1.w;
    }
    {
      int pr = tid >> 2;
      int cb = (tid & 3) * 8;
      const float* s = Ob + (size_t)(pbase + pr) * kC + c0 + cb;
      float4 a0 = *(const float4*)(s);
      float4 a1 = *(const float4*)(s + 4);
      Os[cb + 0][pr] = a0.x; Os[cb + 1][pr] = a0.y; Os[cb + 2][pr] = a0.z; Os[cb + 3][pr] = a0.w;
      Os[cb + 4][pr] = a1.x; Os[cb + 5][pr] = a1.y; Os[cb + 6][pr] = a1.z; Os[cb + 7][pr] = a1.w;
    }
    __syncthreads();
    #pragma unroll
    for (int kk = 0; kk < 32; ++kk) {
      float4 av  = *(const float4*)&Ws[kk][ty * 4];
      float4 bv4 = *(const float4*)&Os[kk][tx * 4];
      float a[4]  = {av.x, av.y, av.z, av.w};
      float bb[4] = {bv4.x, bv4.y, bv4.z, bv4.w};
      #pragma unroll
      for (int i = 0; i < 4; ++i)
        #pragma unroll
        for (int j = 0; j < 4; ++j) acc[i][j] = fmaf(a[i], bb[j], acc[i][j]);
    }
  }
  #pragma unroll
  for (int i = 0; i < 4; ++i) {
    int o = obase + ty * 4 + i;
    float bias = bp[o];
    const float* xr   = x   + ((size_t)b * kC + o) * kHW + pbase + tx * 4;
    float*       orow = out + ((size_t)b * kC + o) * kHW + pbase + tx * 4;
    float4 xv = *(const float4*)xr;
    float4 v = make_float4(acc[i][0] + bias + xv.x, acc[i][1] + bias + xv.y,
                           acc[i][2] + bias + xv.z, acc[i][3] + bias + xv.w);
    *(float4*)orow = v;
  }
}

// ---------------------------------------------------------------------------
extern "C" void kernel_launch(void* const* d_in, const int* in_sizes, int n_in,
                              void* d_out, int out_size, void* d_ws, size_t ws_size,
                              hipStream_t stream) {
  (void)in_sizes; (void)n_in; (void)out_size;
  const float* x     = (const float*)d_in[0];
  const float* y     = (const float*)d_in[1];
  const float* gamma = (const float*)d_in[2];
  const float* beta  = (const float*)d_in[3];
  const float* wq    = (const float*)d_in[4];
  const float* bq    = (const float*)d_in[5];
  const float* wk    = (const float*)d_in[6];
  const float* bk    = (const float*)d_in[7];
  const float* wv    = (const float*)d_in[8];
  const float* bv    = (const float*)d_in[9];
  const float* wp    = (const float*)d_in[10];
  const float* bp    = (const float*)d_in[11];
  float* out = (float*)d_out;

  char* ws = (char*)d_ws;
  size_t bsz = (size_t)kB * kHW * kC * sizeof(unsigned short);  // 16 MB bf16 tensor
  size_t fsz = (size_t)kB * kHW * kC * sizeof(float);           // 32 MB fp32 tensor
  size_t need = 5 * bsz + fsz + 4 * (size_t)kB * kC * sizeof(float);
  if (ws_size < need) return;

  unsigned short* Qh = (unsigned short*)(ws);
  unsigned short* Ql = (unsigned short*)(ws + 1 * bsz);
  unsigned short* Kh = (unsigned short*)(ws + 2 * bsz);
  unsigned short* Kl = (unsigned short*)(ws + 3 * bsz);
  unsigned short* Vh = (unsigned short*)(ws + 4 * bsz);
  float* Ot     = (float*)(ws + 5 * bsz);
  float* scaleX = (float*)(ws + 5 * bsz + fsz);
  float* shiftX = scaleX + kB * kC;
  float* scaleY = shiftX + kB * kC;
  float* shiftY = scaleY + kB * kC;

  gn_stats_kernel<<<dim3(64), dim3(256), 0, stream>>>(
      x, y, gamma, beta, scaleX, shiftX, scaleY, shiftY);
  qkv_gemm_kernel<<<dim3(kB * 64 * 4, 3), dim3(256), 0, stream>>>(
      x, y, wq, bq, wk, bk, wv, bv, scaleX, shiftX, scaleY, shiftY,
      Qh, Ql, Kh, Kl, Vh);
  flash_mfma_kernel<<<dim3(kB * 64), dim3(256), 0, stream>>>(
      Qh, Ql, Kh, Kl, Vh, Ot);
  proj_kernel<<<dim3(kB * 64 * 4), dim3(256), 0, stream>>>(Ot, wp, bp, x, out);
}

// Round 5
// 796.712 us; speedup vs baseline: 4.0444x; 1.2446x over previous
//
#include <hip/hip_runtime.h>
#include <math.h>

// AttnBlock fused pipeline, full-MFMA edition (no setprio — round-5 isolation).
//   x,y: [8, 256, 64, 64] fp32; GN groups=4 eps=1e-6; 4 conv1x1 weights [256,256].
// All GEMMs (qkv, attention, proj) on bf16 MFMA with hi/lo 3-term splitting for
// fp32-class accuracy. Fragment convention validated on HW in round 3:
//   A-frag: m = lane&15, k-slice = (lane>>4)*8 ; B-frag: n = lane&15, same k
//   D: col = lane&15, row = (lane>>4)*4 + reg.
// Workspace: Qh,Ql,Kh,Kl,Vh (bf16, 16MB each) + Ot (fp32, 32MB) + stats.

namespace {
constexpr int kB   = 8;
constexpr int kC   = 256;
constexpr int kCPG = 64;
constexpr int kHW  = 4096;
constexpr float kEps = 1e-6f;
}

typedef short bf16x8 __attribute__((ext_vector_type(8)));   // 8 bf16 in 4 VGPRs
typedef float f32x4  __attribute__((ext_vector_type(4)));

#define MFMA16(a, b, c) __builtin_amdgcn_mfma_f32_16x16x32_bf16((a), (b), (c), 0, 0, 0)

__device__ __forceinline__ unsigned short f2bf(float v) {   // RNE fp32 -> bf16 bits
  unsigned u = __float_as_uint(v);
  u += 0x7FFFu + ((u >> 16) & 1u);
  return (unsigned short)(u >> 16);
}
__device__ __forceinline__ float bf2f(unsigned short h) {
  return __uint_as_float(((unsigned)h) << 16);
}

// ---------------------------------------------------------------------------
// Kernel 1: GroupNorm statistics -> per-(tensor,b,c) scale/shift
// ---------------------------------------------------------------------------
__global__ __launch_bounds__(256)
void gn_stats_kernel(const float* __restrict__ x, const float* __restrict__ y,
                     const float* __restrict__ gamma, const float* __restrict__ beta,
                     float* __restrict__ scaleX, float* __restrict__ shiftX,
                     float* __restrict__ scaleY, float* __restrict__ shiftY) {
  int blk = blockIdx.x;            // t*32 + b*4 + g
  int g = blk & 3;
  int b = (blk >> 2) & 7;
  int t = blk >> 5;
  const float* src = (t == 0 ? x : y) + ((size_t)b * kC + (size_t)g * kCPG) * kHW;
  const int N = kCPG * kHW;
  float sum = 0.f, ssq = 0.f;
  for (int i = threadIdx.x * 4; i < N; i += 256 * 4) {
    float4 v = *(const float4*)(src + i);
    sum += v.x + v.y + v.z + v.w;
    ssq += v.x * v.x + v.y * v.y + v.z * v.z + v.w * v.w;
  }
  #pragma unroll
  for (int off = 32; off > 0; off >>= 1) {
    sum += __shfl_down(sum, off);
    ssq += __shfl_down(ssq, off);
  }
  __shared__ float rs[4], rq[4];
  __shared__ float sM, sR;
  int lane = threadIdx.x & 63, w = threadIdx.x >> 6;
  if (lane == 0) { rs[w] = sum; rq[w] = ssq; }
  __syncthreads();
  if (threadIdx.x == 0) {
    float s = rs[0] + rs[1] + rs[2] + rs[3];
    float q = rq[0] + rq[1] + rq[2] + rq[3];
    float mean = s / (float)N;
    float var  = q / (float)N - mean * mean;
    sM = mean;
    sR = rsqrtf(var + kEps);
  }
  __syncthreads();
  if (threadIdx.x < kCPG) {
    int c = g * kCPG + threadIdx.x;
    float sc = gamma[c] * sR;
    float sh = beta[c] - sM * sc;
    if (t == 0) { scaleX[b * kC + c] = sc; shiftX[b * kC + c] = sh; }
    else        { scaleY[b * kC + c] = sc; shiftY[b * kC + c] = sh; }
  }
}

// ---------------------------------------------------------------------------
// Kernel 2: QKV conv1x1 via bf16 MFMA, hi/lo 3-term (fp32-class).
//   Block: (b, 64-pixel tile) x z; computes all 256 out-channels.
//   Q/K: A=W(m=o), B=Xn(n=p) -> store [p][o] hi/lo.  V: A=Xn(m=p), B=W(n=o)
//   -> store [o][p].  GN affine fused into X staging; 1/16 folded into Q.
// ---------------------------------------------------------------------------
__global__ __launch_bounds__(256, 2)
void qkv_mfma_kernel(const float* __restrict__ x, const float* __restrict__ y,
                     const float* __restrict__ wq, const float* __restrict__ bq,
                     const float* __restrict__ wk, const float* __restrict__ bk,
                     const float* __restrict__ wv, const float* __restrict__ bv,
                     const float* __restrict__ scaleX, const float* __restrict__ shiftX,
                     const float* __restrict__ scaleY, const float* __restrict__ shiftY,
                     unsigned short* __restrict__ Qh, unsigned short* __restrict__ Ql,
                     unsigned short* __restrict__ Kh, unsigned short* __restrict__ Kl,
                     unsigned short* __restrict__ Vh) {
  int z  = blockIdx.y;                 // 0=q (from x), 1=k, 2=v (from y)
  int bi = blockIdx.x;
  int pt = bi & 63;
  int b  = bi >> 6;
  int pbase = pt * 64;
  const float* X    = (z == 0 ? x : y) + (size_t)b * kC * kHW;
  const float* W    = (z == 0 ? wq : (z == 1 ? wk : wv));
  const float* bias = (z == 0 ? bq : (z == 1 ? bk : bv));
  const float* SC   = (z == 0 ? scaleX : scaleY) + b * kC;
  const float* SH   = (z == 0 ? shiftX : shiftY) + b * kC;

  __shared__ short Ws_h[256][40];   // [o][c] +8 pad
  __shared__ short Ws_l[256][40];
  __shared__ short Xs_h[64][40];    // [p][c] +8 pad
  __shared__ short Xs_l[64][40];
  __shared__ float Xt[32][68];      // fp32 transpose staging [c][p]

  int tid  = threadIdx.x;
  int lane = tid & 63;
  int w    = tid >> 6;
  int lrow = lane & 15;
  int lgrp = lane >> 4;

  f32x4 acc[4][4];
  #pragma unroll
  for (int i = 0; i < 4; ++i)
    #pragma unroll
    for (int j = 0; j < 4; ++j) acc[i][j] = (f32x4){0.f, 0.f, 0.f, 0.f};

  for (int c0 = 0; c0 < kC; c0 += 32) {
    __syncthreads();
    {  // ---- stage W row o=tid, 32 c, hi/lo ----
      const float* s = W + (size_t)tid * kC + c0;
      #pragma unroll
      for (int seg = 0; seg < 4; ++seg) {
        float4 a0 = *(const float4*)(s + seg * 8);
        float4 a1 = *(const float4*)(s + seg * 8 + 4);
        float v[8] = {a0.x, a0.y, a0.z, a0.w, a1.x, a1.y, a1.z, a1.w};
        short hh[8], ll[8];
        #pragma unroll
        for (int i = 0; i < 8; ++i) {
          unsigned short h = f2bf(v[i]);
          hh[i] = (short)h;
          ll[i] = (short)f2bf(v[i] - bf2f(h));
        }
        *(bf16x8*)&Ws_h[tid][seg * 8] = *(bf16x8*)hh;
        *(bf16x8*)&Ws_l[tid][seg * 8] = *(bf16x8*)ll;
      }
    }
    {  // ---- stage X [32c][64p] normalized fp32 ----
      int c  = tid >> 3;
      int p8 = (tid & 7) * 8;
      const float* s = X + (size_t)(c0 + c) * kHW + pbase + p8;
      float sc = SC[c0 + c], sh = SH[c0 + c];
      float4 a0 = *(const float4*)(s);
      float4 a1 = *(const float4*)(s + 4);
      float4 r0 = make_float4(fmaf(a0.x, sc, sh), fmaf(a0.y, sc, sh), fmaf(a0.z, sc, sh), fmaf(a0.w, sc, sh));
      float4 r1 = make_float4(fmaf(a1.x, sc, sh), fmaf(a1.y, sc, sh), fmaf(a1.z, sc, sh), fmaf(a1.w, sc, sh));
      *(float4*)&Xt[c][p8]     = r0;
      *(float4*)&Xt[c][p8 + 4] = r1;
    }
    __syncthreads();
    {  // ---- transpose Xt -> Xs[p][c] hi/lo ----
      int p  = tid & 63;
      int cs = (tid >> 6) * 8;
      short hh[8], ll[8];
      #pragma unroll
      for (int i = 0; i < 8; ++i) {
        float v = Xt[cs + i][p];
        unsigned short h = f2bf(v);
        hh[i] = (short)h;
        ll[i] = (short)f2bf(v - bf2f(h));
      }
      *(bf16x8*)&Xs_h[p][cs] = *(bf16x8*)hh;
      *(bf16x8*)&Xs_l[p][cs] = *(bf16x8*)ll;
    }
    __syncthreads();

    // ---- MFMA: 3-term hi/lo ----
    if (z < 2) {
      bf16x8 ah[4], al[4], bh[4], bl[4];
      #pragma unroll
      for (int mt = 0; mt < 4; ++mt) {
        ah[mt] = *(const bf16x8*)&Ws_h[w * 64 + mt * 16 + lrow][lgrp * 8];
        al[mt] = *(const bf16x8*)&Ws_l[w * 64 + mt * 16 + lrow][lgrp * 8];
      }
      #pragma unroll
      for (int nt = 0; nt < 4; ++nt) {
        bh[nt] = *(const bf16x8*)&Xs_h[nt * 16 + lrow][lgrp * 8];
        bl[nt] = *(const bf16x8*)&Xs_l[nt * 16 + lrow][lgrp * 8];
      }
      #pragma unroll
      for (int mt = 0; mt < 4; ++mt)
        #pragma unroll
        for (int nt = 0; nt < 4; ++nt) {
          acc[mt][nt] = MFMA16(ah[mt], bh[nt], acc[mt][nt]);
          acc[mt][nt] = MFMA16(ah[mt], bl[nt], acc[mt][nt]);
          acc[mt][nt] = MFMA16(al[mt], bh[nt], acc[mt][nt]);
        }
    } else {
      bf16x8 ah[4], al[4], bh[4], bl[4];
      #pragma unroll
      for (int mt = 0; mt < 4; ++mt) {
        ah[mt] = *(const bf16x8*)&Xs_h[mt * 16 + lrow][lgrp * 8];
        al[mt] = *(const bf16x8*)&Xs_l[mt * 16 + lrow][lgrp * 8];
      }
      #pragma unroll
      for (int nt = 0; nt < 4; ++nt) {
        bh[nt] = *(const bf16x8*)&Ws_h[w * 64 + nt * 16 + lrow][lgrp * 8];
        bl[nt] = *(const bf16x8*)&Ws_l[w * 64 + nt * 16 + lrow][lgrp * 8];
      }
      #pragma unroll
      for (int mt = 0; mt < 4; ++mt)
        #pragma unroll
        for (int nt = 0; nt < 4; ++nt) {
          acc[mt][nt] = MFMA16(ah[mt], bh[nt], acc[mt][nt]);
          acc[mt][nt] = MFMA16(al[mt], bh[nt], acc[mt][nt]);
          acc[mt][nt] = MFMA16(ah[mt], bl[nt], acc[mt][nt]);
        }
    }
  }

  // ---- epilogue ----
  if (z < 2) {
    float osc = (z == 0) ? 0.0625f : 1.0f;
    unsigned short* Th = ((z == 0) ? Qh : Kh) + (size_t)b * kHW * kC;
    unsigned short* Tl = ((z == 0) ? Ql : Kl) + (size_t)b * kHW * kC;
    #pragma unroll
    for (int mt = 0; mt < 4; ++mt) {
      int o0 = w * 64 + mt * 16 + lgrp * 4;
      float4 b4 = *(const float4*)&bias[o0];
      #pragma unroll
      for (int nt = 0; nt < 4; ++nt) {
        int p = pbase + nt * 16 + lrow;
        ushort4 hh, ll;
        float v0 = (acc[mt][nt][0] + b4.x) * osc;
        float v1 = (acc[mt][nt][1] + b4.y) * osc;
        float v2 = (acc[mt][nt][2] + b4.z) * osc;
        float v3 = (acc[mt][nt][3] + b4.w) * osc;
        hh.x = f2bf(v0); ll.x = f2bf(v0 - bf2f(hh.x));
        hh.y = f2bf(v1); ll.y = f2bf(v1 - bf2f(hh.y));
        hh.z = f2bf(v2); ll.z = f2bf(v2 - bf2f(hh.z));
        hh.w = f2bf(v3); ll.w = f2bf(v3 - bf2f(hh.w));
        *(ushort4*)&Th[(size_t)p * kC + o0] = hh;
        *(ushort4*)&Tl[(size_t)p * kC + o0] = ll;
      }
    }
  } else {
    unsigned short* Vb = Vh + (size_t)b * kHW * kC;   // [o][p]
    #pragma unroll
    for (int nt = 0; nt < 4; ++nt) {
      int o = w * 64 + nt * 16 + lrow;
      float bo = bias[o];
      #pragma unroll
      for (int mt = 0; mt < 4; ++mt) {
        int p0 = pbase + mt * 16 + lgrp * 4;
        ushort4 hh;
        hh.x = f2bf(acc[mt][nt][0] + bo);
        hh.y = f2bf(acc[mt][nt][1] + bo);
        hh.z = f2bf(acc[mt][nt][2] + bo);
        hh.w = f2bf(acc[mt][nt][3] + bo);
        *(ushort4*)&Vb[(size_t)o * kHW + p0] = hh;
      }
    }
  }
}

// ---------------------------------------------------------------------------
// Kernel 3: MFMA flash attention (round-3 structure, no setprio).
// ---------------------------------------------------------------------------
__global__ __launch_bounds__(256, 2)
void flash_mfma_kernel(const unsigned short* __restrict__ Qh, const unsigned short* __restrict__ Ql,
                       const unsigned short* __restrict__ Kh, const unsigned short* __restrict__ Kl,
                       const unsigned short* __restrict__ Vh, float* __restrict__ Ot) {
  int bid = blockIdx.x;
  int b  = bid & 7;
  int qt = bid >> 3;
  const size_t toff = (size_t)b * kHW * kC;
  const unsigned short* Qhb = Qh + toff;
  const unsigned short* Qlb = Ql + toff;
  const unsigned short* Khb = Kh + toff;
  const unsigned short* Klb = Kl + toff;
  const unsigned short* Vhb = Vh + toff;   // [c][k]
  float* O = Ot + toff;                    // [q][c]

  __shared__ short Kh_s[32][264];   // [key][c] +8 pad
  __shared__ short Kl_s[32][264];
  __shared__ short V_s[256][40];    // [c][key] +8 pad
  __shared__ short P_s[64][40];     // [q][key] +8 pad

  int tid  = threadIdx.x;
  int lane = tid & 63;
  int w    = tid >> 6;
  int lrow = lane & 15;
  int lgrp = lane >> 4;

  bf16x8 qfh[8], qfl[8];
  {
    int qrow = qt * 64 + w * 16 + lrow;
    const unsigned short* qb  = Qhb + (size_t)qrow * kC + lgrp * 8;
    const unsigned short* ql_ = Qlb + (size_t)qrow * kC + lgrp * 8;
    #pragma unroll
    for (int cc = 0; cc < 8; ++cc) {
      qfh[cc] = *(const bf16x8*)(qb  + cc * 32);
      qfl[cc] = *(const bf16x8*)(ql_ + cc * 32);
    }
  }

  f32x4 accO[16];
  #pragma unroll
  for (int nt = 0; nt < 16; ++nt) accO[nt] = (f32x4){0.f, 0.f, 0.f, 0.f};
  float m_[4], l_[4];
  #pragma unroll
  for (int r = 0; r < 4; ++r) { m_[r] = -1e30f; l_[r] = 0.f; }

  for (int kt = 0; kt < 128; ++kt) {
    int kbase = kt * 32;
    __syncthreads();
    {
      int colg = tid & 31;
      int r0   = tid >> 5;
      #pragma unroll
      for (int rep = 0; rep < 4; ++rep) {
        int row = r0 + rep * 8;
        *(int4*)&Kh_s[row][colg * 8] =
            *(const int4*)(Khb + (size_t)(kbase + row) * kC + colg * 8);
        *(int4*)&Kl_s[row][colg * 8] =
            *(const int4*)(Klb + (size_t)(kbase + row) * kC + colg * 8);
      }
      int part = tid & 3;
      int c0   = tid >> 2;
      #pragma unroll
      for (int rep = 0; rep < 4; ++rep) {
        int c = c0 + rep * 64;
        *(int4*)&V_s[c][part * 8] =
            *(const int4*)(Vhb + (size_t)c * kHW + kbase + part * 8);
      }
    }
    __syncthreads();

    f32x4 s0 = (f32x4){0.f, 0.f, 0.f, 0.f};
    f32x4 s1 = (f32x4){0.f, 0.f, 0.f, 0.f};
    #pragma unroll
    for (int cc = 0; cc < 8; ++cc) {
      int coff = cc * 32 + lgrp * 8;
      bf16x8 k0h = *(const bf16x8*)&Kh_s[lrow][coff];
      bf16x8 k0l = *(const bf16x8*)&Kl_s[lrow][coff];
      bf16x8 k1h = *(const bf16x8*)&Kh_s[16 + lrow][coff];
      bf16x8 k1l = *(const bf16x8*)&Kl_s[16 + lrow][coff];
      s0 = MFMA16(qfh[cc], k0h, s0);
      s0 = MFMA16(qfh[cc], k0l, s0);
      s0 = MFMA16(qfl[cc], k0h, s0);
      s1 = MFMA16(qfh[cc], k1h, s1);
      s1 = MFMA16(qfh[cc], k1l, s1);
      s1 = MFMA16(qfl[cc], k1h, s1);
    }

    int prow = w * 16 + lgrp * 4;
    #pragma unroll
    for (int r = 0; r < 4; ++r) {
      float mx = fmaxf(s0[r], s1[r]);
      mx = fmaxf(mx, __shfl_xor(mx, 1));
      mx = fmaxf(mx, __shfl_xor(mx, 2));
      mx = fmaxf(mx, __shfl_xor(mx, 4));
      mx = fmaxf(mx, __shfl_xor(mx, 8));
      float mn = fmaxf(m_[r], mx);
      float f  = __expf(m_[r] - mn);
      unsigned short u0 = f2bf(__expf(s0[r] - mn));
      unsigned short u1 = f2bf(__expf(s1[r] - mn));
      float sum = bf2f(u0) + bf2f(u1);
      sum += __shfl_xor(sum, 1);
      sum += __shfl_xor(sum, 2);
      sum += __shfl_xor(sum, 4);
      sum += __shfl_xor(sum, 8);
      l_[r] = l_[r] * f + sum;
      m_[r] = mn;
      P_s[prow + r][lrow]      = (short)u0;
      P_s[prow + r][16 + lrow] = (short)u1;
      #pragma unroll
      for (int nt = 0; nt < 16; ++nt) accO[nt][r] *= f;
    }
    __syncthreads();

    bf16x8 pa = *(const bf16x8*)&P_s[w * 16 + lrow][lgrp * 8];
    #pragma unroll
    for (int nt = 0; nt < 16; ++nt) {
      bf16x8 vb = *(const bf16x8*)&V_s[nt * 16 + lrow][lgrp * 8];
      accO[nt] = MFMA16(pa, vb, accO[nt]);
    }
  }

  float inv[4];
  #pragma unroll
  for (int r = 0; r < 4; ++r) inv[r] = 1.0f / l_[r];
  int qbase = qt * 64 + w * 16 + lgrp * 4;
  #pragma unroll
  for (int nt = 0; nt < 16; ++nt) {
    #pragma unroll
    for (int r = 0; r < 4; ++r) {
      O[(size_t)(qbase + r) * kC + nt * 16 + lrow] = accO[nt][r] * inv[r];
    }
  }
}

// ---------------------------------------------------------------------------
// Kernel 4: proj conv1x1 + residual via bf16 MFMA, hi/lo 3-term.
//   A = O_attn[p][c] (m=p), B = Wp[o][c] (n=o) -> D[p][o]; out[o][p] f32.
// ---------------------------------------------------------------------------
__global__ __launch_bounds__(256, 2)
void proj_mfma_kernel(const float* __restrict__ Ot, const float* __restrict__ wp,
                      const float* __restrict__ bp, const float* __restrict__ x,
                      float* __restrict__ out) {
  int bi = blockIdx.x;
  int pt = bi & 63;
  int b  = bi >> 6;
  int pbase = pt * 64;
  const float* Ob = Ot + (size_t)b * kHW * kC;   // [p][c]

  __shared__ short Ws_h[256][40];   // [o][c]
  __shared__ short Ws_l[256][40];
  __shared__ short Os_h[64][40];    // [p][c]
  __shared__ short Os_l[64][40];

  int tid  = threadIdx.x;
  int lane = tid & 63;
  int w    = tid >> 6;
  int lrow = lane & 15;
  int lgrp = lane >> 4;

  f32x4 acc[4][4];
  #pragma unroll
  for (int i = 0; i < 4; ++i)
    #pragma unroll
    for (int j = 0; j < 4; ++j) acc[i][j] = (f32x4){0.f, 0.f, 0.f, 0.f};

  for (int c0 = 0; c0 < kC; c0 += 32) {
    __syncthreads();
    {  // stage Wp row o=tid
      const float* s = wp + (size_t)tid * kC + c0;
      #pragma unroll
      for (int seg = 0; seg < 4; ++seg) {
        float4 a0 = *(const float4*)(s + seg * 8);
        float4 a1 = *(const float4*)(s + seg * 8 + 4);
        float v[8] = {a0.x, a0.y, a0.z, a0.w, a1.x, a1.y, a1.z, a1.w};
        short hh[8], ll[8];
        #pragma unroll
        for (int i = 0; i < 8; ++i) {
          unsigned short h = f2bf(v[i]);
          hh[i] = (short)h;
          ll[i] = (short)f2bf(v[i] - bf2f(h));
        }
        *(bf16x8*)&Ws_h[tid][seg * 8] = *(bf16x8*)hh;
        *(bf16x8*)&Ws_l[tid][seg * 8] = *(bf16x8*)ll;
      }
    }
    {  // stage O tile [64p][32c] hi/lo (Ot already [p][c])
      int p  = tid >> 2;
      int c8 = (tid & 3) * 8;
      const float* s = Ob + (size_t)(pbase + p) * kC + c0 + c8;
      float4 a0 = *(const float4*)(s);
      float4 a1 = *(const float4*)(s + 4);
      float v[8] = {a0.x, a0.y, a0.z, a0.w, a1.x, a1.y, a1.z, a1.w};
      short hh[8], ll[8];
      #pragma unroll
      for (int i = 0; i < 8; ++i) {
        unsigned short h = f2bf(v[i]);
        hh[i] = (short)h;
        ll[i] = (short)f2bf(v[i] - bf2f(h));
      }
      *(bf16x8*)&Os_h[p][c8] = *(bf16x8*)hh;
      *(bf16x8*)&Os_l[p][c8] = *(bf16x8*)ll;
    }
    __syncthreads();

    bf16x8 ah[4], al[4], bh[4], bl[4];
    #pragma unroll
    for (int mt = 0; mt < 4; ++mt) {
      ah[mt] = *(const bf16x8*)&Os_h[mt * 16 + lrow][lgrp * 8];
      al[mt] = *(const bf16x8*)&Os_l[mt * 16 + lrow][lgrp * 8];
    }
    #pragma unroll
    for (int nt = 0; nt < 4; ++nt) {
      bh[nt] = *(const bf16x8*)&Ws_h[w * 64 + nt * 16 + lrow][lgrp * 8];
      bl[nt] = *(const bf16x8*)&Ws_l[w * 64 + nt * 16 + lrow][lgrp * 8];
    }
    #pragma unroll
    for (int mt = 0; mt < 4; ++mt)
      #pragma unroll
      for (int nt = 0; nt < 4; ++nt) {
        acc[mt][nt] = MFMA16(ah[mt], bh[nt], acc[mt][nt]);
        acc[mt][nt] = MFMA16(al[mt], bh[nt], acc[mt][nt]);
        acc[mt][nt] = MFMA16(ah[mt], bl[nt], acc[mt][nt]);
      }
  }

  // epilogue: out[b][o][p] = acc + bp[o] + x[b][o][p]
  #pragma unroll
  for (int nt = 0; nt < 4; ++nt) {
    int o = w * 64 + nt * 16 + lrow;
    float bo = bp[o];
    #pragma unroll
    for (int mt = 0; mt < 4; ++mt) {
      int p0 = pbase + mt * 16 + lgrp * 4;
      const float* xr   = x   + ((size_t)b * kC + o) * kHW + p0;
      float*       orow = out + ((size_t)b * kC + o) * kHW + p0;
      float4 xv = *(const float4*)xr;
      float4 v = make_float4(acc[mt][nt][0] + bo + xv.x, acc[mt][nt][1] + bo + xv.y,
                             acc[mt][nt][2] + bo + xv.z, acc[mt][nt][3] + bo + xv.w);
      *(float4*)orow = v;
    }
  }
}

// ---------------------------------------------------------------------------
extern "C" void kernel_launch(void* const* d_in, const int* in_sizes, int n_in,
                              void* d_out, int out_size, void* d_ws, size_t ws_size,
                              hipStream_t stream) {
  (void)in_sizes; (void)n_in; (void)out_size;
  const float* x     = (const float*)d_in[0];
  const float* y     = (const float*)d_in[1];
  const float* gamma = (const float*)d_in[2];
  const float* beta  = (const float*)d_in[3];
  const float* wq    = (const float*)d_in[4];
  const float* bq    = (const float*)d_in[5];
  const float* wk    = (const float*)d_in[6];
  const float* bk    = (const float*)d_in[7];
  const float* wv    = (const float*)d_in[8];
  const float* bv    = (const float*)d_in[9];
  const float* wp    = (const float*)d_in[10];
  const float* bp    = (const float*)d_in[11];
  float* out = (float*)d_out;

  char* ws = (char*)d_ws;
  size_t bsz = (size_t)kB * kHW * kC * sizeof(unsigned short);  // 16 MB bf16 tensor
  size_t fsz = (size_t)kB * kHW * kC * sizeof(float);           // 32 MB fp32 tensor
  size_t need = 5 * bsz + fsz + 4 * (size_t)kB * kC * sizeof(float);
  if (ws_size < need) return;

  unsigned short* Qh = (unsigned short*)(ws);
  unsigned short* Ql = (unsigned short*)(ws + 1 * bsz);
  unsigned short* Kh = (unsigned short*)(ws + 2 * bsz);
  unsigned short* Kl = (unsigned short*)(ws + 3 * bsz);
  unsigned short* Vh = (unsigned short*)(ws + 4 * bsz);
  float* Ot     = (float*)(ws + 5 * bsz);
  float* scaleX = (float*)(ws + 5 * bsz + fsz);
  float* shiftX = scaleX + kB * kC;
  float* scaleY = shiftX + kB * kC;
  float* shiftY = scaleY + kB * kC;

  gn_stats_kernel<<<dim3(64), dim3(256), 0, stream>>>(
      x, y, gamma, beta, scaleX, shiftX, scaleY, shiftY);
  qkv_mfma_kernel<<<dim3(kB * 64, 3), dim3(256), 0, stream>>>(
      x, y, wq, bq, wk, bk, wv, bv, scaleX, shiftX, scaleY, shiftY,
      Qh, Ql, Kh, Kl, Vh);
  flash_mfma_kernel<<<dim3(kB * 64), dim3(256), 0, stream>>>(
      Qh, Ql, Kh, Kl, Vh, Ot);
  proj_mfma_kernel<<<dim3(kB * 64), dim3(256), 0, stream>>>(Ot, wp, bp, x, out);
}